// Round 1
// baseline (14231.409 us; speedup 1.0000x reference)
//
#include <hip/hip_runtime.h>
#include <hip/hip_fp16.h>

#define B_ 128
#define T_ 512
#define E_ 128
#define D_ 128

// 2*log2(e): exp2(C2*x) == e^(2x)
#define C2f 2.885390081777927f
#define L2E 1.4426950408889634f

__device__ __forceinline__ float rcpf_(float x){ return __builtin_amdgcn_rcpf(x); }
__device__ __forceinline__ float ex2_(float x){ return __builtin_amdgcn_exp2f(x); }

// Pack rows 2p,2p+1 of a (2R x 512) fp32 matrix into half2 (R x 512).
__global__ __launch_bounds__(256) void pack_pairs(const float* __restrict__ W,
                                                  __half2* __restrict__ Wp, int npairs){
    int idx = blockIdx.x * 256 + threadIdx.x;
    if (idx < npairs * 512){
        int p = idx >> 9, n = idx & 511;
        Wp[idx] = __floats2half2_rn(W[(2*p)*512 + n], W[(2*p+1)*512 + n]);
    }
}

// P[b][n][t] = exp2(C2 * (sum_e enc[b][t][e]*Ua[e][n] + bu[n]))  as fp16
__global__ __launch_bounds__(256) void uenc_kernel(const float* __restrict__ enc,
                                                   const float* __restrict__ Ua,
                                                   const float* __restrict__ bu,
                                                   __half* __restrict__ P){
    int b = blockIdx.z;
    int t0 = blockIdx.x * 64;
    int n0 = blockIdx.y * 64;
    int tt = threadIdx.x & 63;   // lane = t' within tile
    int ng = threadIdx.x >> 6;   // wave id = n-subtile (uniform per wave)
    const float* erow = enc + ((size_t)b * T_ + (t0 + tt)) * E_;
    const float* uap  = Ua + n0 + ng * 16;
    float acc[16];
    #pragma unroll
    for (int i = 0; i < 16; i++) acc[i] = 0.f;
    #pragma unroll 2
    for (int e = 0; e < E_; e++){
        float a = erow[e];
        const float4* u4 = (const float4*)(uap + (size_t)e * T_);
        float4 x0 = u4[0], x1 = u4[1], x2 = u4[2], x3 = u4[3];
        acc[0]  = fmaf(a, x0.x, acc[0]);  acc[1]  = fmaf(a, x0.y, acc[1]);
        acc[2]  = fmaf(a, x0.z, acc[2]);  acc[3]  = fmaf(a, x0.w, acc[3]);
        acc[4]  = fmaf(a, x1.x, acc[4]);  acc[5]  = fmaf(a, x1.y, acc[5]);
        acc[6]  = fmaf(a, x1.z, acc[6]);  acc[7]  = fmaf(a, x1.w, acc[7]);
        acc[8]  = fmaf(a, x2.x, acc[8]);  acc[9]  = fmaf(a, x2.y, acc[9]);
        acc[10] = fmaf(a, x2.z, acc[10]); acc[11] = fmaf(a, x2.w, acc[11]);
        acc[12] = fmaf(a, x3.x, acc[12]); acc[13] = fmaf(a, x3.y, acc[13]);
        acc[14] = fmaf(a, x3.z, acc[14]); acc[15] = fmaf(a, x3.w, acc[15]);
    }
    int nb = n0 + ng * 16;
    #pragma unroll
    for (int i = 0; i < 16; i++){
        float u = acc[i] + bu[nb + i];
        P[(size_t)b * T_ * T_ + (size_t)(nb + i) * T_ + t0 + tt] = __float2half(ex2_(C2f * u));
    }
}

__global__ __launch_bounds__(1024) void decoder_kernel(
    const float* __restrict__ enc, const float* __restrict__ labels,
    const float* __restrict__ init_h, const float* __restrict__ init_c,
    const float* __restrict__ init_ctx,
    const float* __restrict__ ba, const float* __restrict__ Va,
    const float* __restrict__ Wc, const float* __restrict__ bc,
    const float* __restrict__ Wk, const float* __restrict__ bl,
    const float* __restrict__ W1, const float* __restrict__ b1,
    const float* __restrict__ W2, const float* __restrict__ b2,
    const __half2* __restrict__ Wa_p, const __half2* __restrict__ Wr_p,
    const unsigned int* __restrict__ Pw, float* __restrict__ out)
{
    __shared__ __align__(16) float h_s[128], c_s[128], ctx_s[128];
    __shared__ __align__(16) float2 QV[512];     // .x = Q[n] (rewritten each step), .y = -2*Va[n]
    __shared__ __align__(16) float sc[512];      // scores -> softmax w -> z
    __shared__ __align__(16) float scratch[2048];
    __shared__ __align__(16) float ba_s[512], bl_s[512], Wk_s[512];
    __shared__ float Wc_s[132];
    __shared__ float red[24];

    int tid = threadIdx.x;
    int b = blockIdx.x;

    if (tid < 128){
        h_s[tid]   = init_h[b*128 + tid];
        c_s[tid]   = init_c[b*128 + tid];
        ctx_s[tid] = init_ctx[b*128 + tid];
    }
    if (tid < 512){
        QV[tid].y = -2.f * Va[tid];
        ba_s[tid] = ba[tid];
        bl_s[tid] = bl[tid];
        Wk_s[tid] = Wk[tid];
    }
    if (tid < 129) Wc_s[tid] = Wc[tid];
    __syncthreads();

    const unsigned int* Pb = Pw + (size_t)b * (T_ * (T_/2));

    for (int t = 0; t < T_; t++){
        // ---- phase 1: s[n] = [h;c]@Wa + ba  ->  Q[n] = exp2(C2*s)
        {
            int n = tid & 511, kh = tid >> 9;
            float acc = kh ? 0.f : ba_s[n];
            const float2* hcp = (const float2*)(kh ? c_s : h_s);
            const __half2* wp = Wa_p + (size_t)(kh * 64) * 512 + n;
            #pragma unroll 4
            for (int j = 0; j < 64; j++){
                float2 hv = hcp[j];
                float2 wv = __half22float2(wp[(size_t)j * 512]);
                acc = fmaf(hv.x, wv.x, fmaf(hv.y, wv.y, acc));
            }
            scratch[kh*512 + n] = acc;
        }
        __syncthreads();
        if (tid < 512){
            float s = scratch[tid] + scratch[512 + tid];
            QV[tid].x = ex2_(C2f * s);
        }
        __syncthreads();

        // ---- phase 2: score'[t'] = sum_n (-2 Va[n]) / (P[n,t']*Q[n] + 1)
        {
            int q = tid & 255, nh = tid >> 8;   // t' pair (2q,2q+1), n-quarter nh
            float a0 = 0.f, a1 = 0.f;
            const unsigned int* pp = Pb + q;
            int nbeg = nh * 128;
            #pragma unroll 4
            for (int n = nbeg; n < nbeg + 128; n++){
                unsigned int pv = pp[(size_t)n * 256];
                float2 qv = QV[n];
                __half2 ph = *reinterpret_cast<const __half2*>(&pv);
                float2 pf = __half22float2(ph);
                float m0 = fmaf(pf.x, qv.x, 1.f);
                float m1 = fmaf(pf.y, qv.x, 1.f);
                a0 = fmaf(rcpf_(m0), qv.y, a0);
                a1 = fmaf(rcpf_(m1), qv.y, a1);
            }
            ((float2*)scratch)[nh*256 + q] = make_float2(a0, a1);
        }
        __syncthreads();

        // ---- phase 3: softmax over t' (constant shift dropped: softmax-invariant)
        if (tid < 512){
            float v = scratch[tid] + scratch[512+tid] + scratch[1024+tid] + scratch[1536+tid];
            sc[tid] = v;
            float m = v;
            #pragma unroll
            for (int off = 32; off; off >>= 1) m = fmaxf(m, __shfl_xor(m, off));
            if ((tid & 63) == 0) red[tid >> 6] = m;
        }
        __syncthreads();
        if (tid < 512){
            float m = red[0];
            #pragma unroll
            for (int i = 1; i < 8; i++) m = fmaxf(m, red[i]);
            float p = ex2_((sc[tid] - m) * L2E);
            sc[tid] = p;
            float ss = p;
            #pragma unroll
            for (int off = 32; off; off >>= 1) ss += __shfl_xor(ss, off);
            if ((tid & 63) == 0) red[8 + (tid >> 6)] = ss;
        }
        __syncthreads();
        if (tid < 512){
            float dn = red[8];
            #pragma unroll
            for (int i = 9; i < 16; i++) dn += red[i];
            sc[tid] = sc[tid] * rcpf_(dn);
        }
        __syncthreads();

        // ---- phase 4: ctx[e] = sum_t w[t]*enc[b,t,e]  (fp32 exact)
        {
            int e = tid & 127, tg = tid >> 7;
            float acc = 0.f;
            const float* ep = enc + ((size_t)b * T_ + tg * 64) * E_ + e;
            #pragma unroll 4
            for (int i = 0; i < 64; i++)
                acc = fmaf(sc[tg*64 + i], ep[(size_t)i * E_], acc);
            scratch[tg*128 + e] = acc;
        }
        __syncthreads();
        if (tid < 128){
            float s = 0.f;
            #pragma unroll
            for (int i = 0; i < 8; i++) s += scratch[i*128 + tid];
            ctx_s[tid] = s;
        }
        __syncthreads();

        // ---- phase 5a: rW[m] = h@Wr + bl
        {
            int m = tid & 511, kh = tid >> 9;
            float acc = kh ? 0.f : bl_s[m];
            const float2* hp = (const float2*)h_s;
            const __half2* wp = Wr_p + (size_t)(kh * 32) * 512 + m;
            #pragma unroll 4
            for (int j = 0; j < 32; j++){
                float2 hv = hp[kh*32 + j];
                float2 wv = __half22float2(wp[(size_t)j * 512]);
                acc = fmaf(hv.x, wv.x, fmaf(hv.y, wv.y, acc));
            }
            scratch[kh*512 + m] = acc;
        }
        __syncthreads();
        // ---- phase 5b: y = [label, ctx] @ Wc + bc
        if (tid < 64){
            float a = ctx_s[tid]*Wc_s[1+tid] + ctx_s[64+tid]*Wc_s[65+tid];
            #pragma unroll
            for (int off = 32; off; off >>= 1) a += __shfl_xor(a, off);
            if (tid == 0) red[16] = fmaf(labels[(size_t)b * T_ + t], Wc_s[0], a + bc[0]);
        }
        __syncthreads();
        // ---- phase 5c: z = y*Wk + rW
        if (tid < 512){
            sc[tid] = scratch[tid] + scratch[512 + tid] + red[16] * Wk_s[tid];
        }
        __syncthreads();
        // ---- phase 5d: gates (Keras order i,f,g,o)
        if (tid < 128){
            float zi = sc[tid], zf = sc[128+tid], zg = sc[256+tid], zo = sc[384+tid];
            float si = rcpf_(1.f + ex2_(-L2E * zi));
            float sf = rcpf_(1.f + ex2_(-L2E * zf));
            float so = rcpf_(1.f + ex2_(-L2E * zo));
            float tg_ = 1.f - 2.f * rcpf_(ex2_(C2f * zg) + 1.f);
            float cn = sf * c_s[tid] + si * tg_;
            float tc = 1.f - 2.f * rcpf_(ex2_(C2f * cn) + 1.f);
            c_s[tid] = cn;
            h_s[tid] = so * tc;
        }
        __syncthreads();
    }

    // ---- epilogue: pred = ([h, ctx] @ W1 + b1) @ W2 + b2
    if (tid < 128){
        float acc = b1[tid];
        for (int k = 0; k < 128; k++) acc = fmaf(h_s[k],   W1[k*128 + tid], acc);
        for (int k = 0; k < 128; k++) acc = fmaf(ctx_s[k], W1[(128+k)*128 + tid], acc);
        scratch[tid] = acc * W2[tid];
    }
    __syncthreads();
    if (tid < 64){
        float a = scratch[tid] + scratch[64 + tid];
        #pragma unroll
        for (int off = 32; off; off >>= 1) a += __shfl_xor(a, off);
        if (tid == 0) out[b] = a + b2[0];
    }
}

extern "C" void kernel_launch(void* const* d_in, const int* in_sizes, int n_in,
                              void* d_out, int out_size, void* d_ws, size_t ws_size,
                              hipStream_t stream){
    const float* enc      = (const float*)d_in[0];
    const float* labels   = (const float*)d_in[1];
    const float* init_h   = (const float*)d_in[2];
    const float* init_c   = (const float*)d_in[3];
    const float* init_ctx = (const float*)d_in[4];
    const float* Wa = (const float*)d_in[5];
    const float* ba = (const float*)d_in[6];
    const float* Ua = (const float*)d_in[7];
    const float* bu = (const float*)d_in[8];
    const float* Va = (const float*)d_in[9];
    // d_in[10] = bv: softmax-shift-invariant, unused
    const float* Wc = (const float*)d_in[11];
    const float* bc = (const float*)d_in[12];
    const float* Wk = (const float*)d_in[13];
    const float* Wr = (const float*)d_in[14];
    const float* bl = (const float*)d_in[15];
    const float* W1 = (const float*)d_in[16];
    const float* b1 = (const float*)d_in[17];
    const float* W2 = (const float*)d_in[18];
    const float* b2 = (const float*)d_in[19];

    char* ws = (char*)d_ws;
    __half*  P    = (__half*)ws;                               // 128*512*512*2 = 67108864 B
    __half2* Wa_p = (__half2*)(ws + 67108864);                 // 128*512*4 = 262144 B
    __half2* Wr_p = (__half2*)(ws + 67108864 + 262144);        // 64*512*4  = 131072 B

    pack_pairs<<<256, 256, 0, stream>>>(Wa, Wa_p, 128);
    pack_pairs<<<128, 256, 0, stream>>>(Wr, Wr_p, 64);

    dim3 g1(T_/64, T_/64, B_);
    uenc_kernel<<<g1, 256, 0, stream>>>(enc, Ua, bu, P);

    decoder_kernel<<<B_, 1024, 0, stream>>>(enc, labels, init_h, init_c, init_ctx,
        ba, Va, Wc, bc, Wk, bl, W1, b1, W2, b2,
        Wa_p, Wr_p, (const unsigned int*)P, (float*)d_out);
}

// Round 2
// 13806.879 us; speedup vs baseline: 1.0307x; 1.0307x over previous
//
#include <hip/hip_runtime.h>
#include <hip/hip_fp16.h>

#define B_ 128
#define T_ 512
#define E_ 128
#define D_ 128

// exp2(C2*x) == e^(2x);  L2E = log2(e)
#define C2f 2.885390081777927f
#define L2E 1.4426950408889634f

__device__ __forceinline__ float rcpf_(float x){ return __builtin_amdgcn_rcpf(x); }
__device__ __forceinline__ float ex2_(float x){ return __builtin_amdgcn_exp2f(x); }

// out[n][k] = (half) in[k][n],  K x N input, 32x32 tiles, 256 threads.
// blockIdx.z selects a slab of K*N elements (for batched use).
__global__ __launch_bounds__(256) void transpose_half(const float* __restrict__ in,
                                                      __half* __restrict__ out,
                                                      int K, int N){
    __shared__ float tile[32][33];
    const float* inz = in + (size_t)blockIdx.z * K * N;
    __half* outz = out + (size_t)blockIdx.z * K * N;
    int n0 = blockIdx.x * 32, k0 = blockIdx.y * 32;
    int tx = threadIdx.x & 31, ty = threadIdx.x >> 5;   // ty 0..7
    #pragma unroll
    for (int i = ty; i < 32; i += 8)
        tile[i][tx] = inz[(size_t)(k0 + i) * N + n0 + tx];
    __syncthreads();
    #pragma unroll
    for (int i = ty; i < 32; i += 8)
        outz[(size_t)(n0 + i) * K + k0 + tx] = __float2half(tile[tx][i]);
}

// P[b][n][t] = exp2(C2 * (sum_e enc[b][t][e]*Ua[e][n] + bu[n]))  as fp16
__global__ __launch_bounds__(256) void uenc_kernel(const float* __restrict__ enc,
                                                   const float* __restrict__ Ua,
                                                   const float* __restrict__ bu,
                                                   __half* __restrict__ P){
    int b = blockIdx.z;
    int t0 = blockIdx.x * 64;
    int n0 = blockIdx.y * 64;
    int tt = threadIdx.x & 63;   // lane = t' within tile
    int ng = threadIdx.x >> 6;   // wave id = n-subtile (uniform per wave)
    const float* erow = enc + ((size_t)b * T_ + (t0 + tt)) * E_;
    const float* uap  = Ua + n0 + ng * 16;
    float acc[16];
    #pragma unroll
    for (int i = 0; i < 16; i++) acc[i] = 0.f;
    #pragma unroll 2
    for (int e0 = 0; e0 < E_; e0 += 4){
        float4 av = *(const float4*)(erow + e0);
        #pragma unroll
        for (int ee = 0; ee < 4; ee++){
            float a = (ee==0)?av.x:(ee==1)?av.y:(ee==2)?av.z:av.w;
            const float4* u4 = (const float4*)(uap + (size_t)(e0+ee) * T_);
            float4 x0 = u4[0], x1 = u4[1], x2 = u4[2], x3 = u4[3];
            acc[0]  = fmaf(a, x0.x, acc[0]);  acc[1]  = fmaf(a, x0.y, acc[1]);
            acc[2]  = fmaf(a, x0.z, acc[2]);  acc[3]  = fmaf(a, x0.w, acc[3]);
            acc[4]  = fmaf(a, x1.x, acc[4]);  acc[5]  = fmaf(a, x1.y, acc[5]);
            acc[6]  = fmaf(a, x1.z, acc[6]);  acc[7]  = fmaf(a, x1.w, acc[7]);
            acc[8]  = fmaf(a, x2.x, acc[8]);  acc[9]  = fmaf(a, x2.y, acc[9]);
            acc[10] = fmaf(a, x2.z, acc[10]); acc[11] = fmaf(a, x2.w, acc[11]);
            acc[12] = fmaf(a, x3.x, acc[12]); acc[13] = fmaf(a, x3.y, acc[13]);
            acc[14] = fmaf(a, x3.z, acc[14]); acc[15] = fmaf(a, x3.w, acc[15]);
        }
    }
    int nb = n0 + ng * 16;
    #pragma unroll
    for (int i = 0; i < 16; i++){
        float u = acc[i] + bu[nb + i];
        P[(size_t)b * T_ * T_ + (size_t)(nb + i) * T_ + t0 + tt] = __float2half(ex2_(C2f * u));
    }
}

// 8 half-weights (uint4) dotted against 8 f32 activations (2x float4) -> acc
__device__ __forceinline__ void dot8(float& acc, uint4 wv, float4 ha, float4 hb){
    float2 f0 = __half22float2(*reinterpret_cast<__half2*>(&wv.x));
    float2 f1 = __half22float2(*reinterpret_cast<__half2*>(&wv.y));
    float2 f2 = __half22float2(*reinterpret_cast<__half2*>(&wv.z));
    float2 f3 = __half22float2(*reinterpret_cast<__half2*>(&wv.w));
    acc = fmaf(ha.x, f0.x, acc); acc = fmaf(ha.y, f0.y, acc);
    acc = fmaf(ha.z, f1.x, acc); acc = fmaf(ha.w, f1.y, acc);
    acc = fmaf(hb.x, f2.x, acc); acc = fmaf(hb.y, f2.y, acc);
    acc = fmaf(hb.z, f3.x, acc); acc = fmaf(hb.w, f3.y, acc);
}

__global__ __launch_bounds__(1024, 4) void decoder_kernel(
    const float* __restrict__ enc, const float* __restrict__ labels,
    const float* __restrict__ init_h, const float* __restrict__ init_c,
    const float* __restrict__ Va,
    const float* __restrict__ ba, const float* __restrict__ bl,
    const float* __restrict__ Wc, const float* __restrict__ bc,
    const float* __restrict__ Wk,
    const float* __restrict__ W1, const float* __restrict__ b1,
    const float* __restrict__ W2, const float* __restrict__ b2,
    const __half* __restrict__ Wa_t, const __half* __restrict__ Wr_t,
    const __half* __restrict__ Pw, float* __restrict__ out)
{
    __shared__ __align__(16) float hc_s[256];     // h [0,128), c [128,256)
    __shared__ __align__(16) float ctx_s[128];
    __shared__ __align__(16) float2 QV[512];      // .x = Q[n] per step, .y = -2*Va[n]
    __shared__ __align__(16) float sc[512];       // softmax numerators p[t]
    __shared__ __align__(16) float rz[512];       // h@Wr + bl
    __shared__ __align__(16) float scratch[8192]; // 32 KB partials
    __shared__ __align__(16) float ba_s[512], bl_s[512], Wk_s[512], lab_s[512];
    __shared__ float Wc_s[132];                   // [0..129) Wc, [130] = bc
    __shared__ float red[20];

    int tid = threadIdx.x;
    int b = blockIdx.x;

    if (tid < 128){
        hc_s[tid]       = init_h[b*128 + tid];
        hc_s[128 + tid] = init_c[b*128 + tid];
    }
    if (tid < 512){
        QV[tid].y = -2.f * Va[tid];
        ba_s[tid] = ba[tid];
        bl_s[tid] = bl[tid];
        Wk_s[tid] = Wk[tid];
        lab_s[tid] = labels[(size_t)b * T_ + tid];
    }
    if (tid < 129) Wc_s[tid] = Wc[tid];
    if (tid == 129) Wc_s[130] = bc[0];
    __syncthreads();

    const __half* Pb = Pw + (size_t)b * (T_ * T_);
    const float4* hc4 = (const float4*)hc_s;

    for (int t = 0; t < T_; t++){
        // ---- phase A (merged): s[n] = [h;c]@Wa + ba  and  rz[m] = h@Wr + bl
        {
            int n = tid & 511, kh = tid >> 9;
            float acc  = kh ? 0.f : ba_s[n];
            float accr = kh ? 0.f : bl_s[n];
            const uint4* wa = (const uint4*)(Wa_t + (size_t)n * 256 + kh * 128);
            #pragma unroll 4
            for (int i = 0; i < 16; i++){
                uint4 wv = wa[i];
                float4 ha = hc4[kh*32 + 2*i], hb = hc4[kh*32 + 2*i + 1];
                dot8(acc, wv, ha, hb);
            }
            const uint4* wr = (const uint4*)(Wr_t + (size_t)n * 128 + kh * 64);
            #pragma unroll 4
            for (int i = 0; i < 8; i++){
                uint4 wv = wr[i];
                float4 ha = hc4[kh*16 + 2*i], hb = hc4[kh*16 + 2*i + 1];
                dot8(accr, wv, ha, hb);
            }
            scratch[kh*512 + n] = acc;
            scratch[1024 + kh*512 + n] = accr;
        }
        __syncthreads();
        // ---- combine: Q[n] = exp2(C2*s[n]);  rz[m]
        if (tid < 512){
            float s = scratch[tid] + scratch[512 + tid];
            QV[tid].x = ex2_(C2f * s);
        } else {
            int m = tid - 512;
            rz[m] = scratch[1024 + m] + scratch[1536 + m];
        }
        __syncthreads();

        // ---- phase B: partial score[t'] = sum_n (-2 Va[n]) / (P[n,t']*Q[n] + 1)
        {
            int q = tid & 63;   // t' octet: t' = 8q .. 8q+7
            int g = tid >> 6;   // n-group: n in [32g, 32g+32)
            float a0=0.f,a1=0.f,a2=0.f,a3=0.f,a4=0.f,a5=0.f,a6=0.f,a7=0.f;
            const uint4* Pq = (const uint4*)Pb + (size_t)g*32*64 + q;
            #pragma unroll 4
            for (int j = 0; j < 32; j++){
                uint4 pv = Pq[(size_t)j * 64];
                float2 qv = QV[g*32 + j];     // wave-uniform broadcast
                float2 f0 = __half22float2(*reinterpret_cast<__half2*>(&pv.x));
                float2 f1 = __half22float2(*reinterpret_cast<__half2*>(&pv.y));
                float2 f2 = __half22float2(*reinterpret_cast<__half2*>(&pv.z));
                float2 f3 = __half22float2(*reinterpret_cast<__half2*>(&pv.w));
                float m;
                m = fmaf(f0.x, qv.x, 1.f); a0 = fmaf(rcpf_(m), qv.y, a0);
                m = fmaf(f0.y, qv.x, 1.f); a1 = fmaf(rcpf_(m), qv.y, a1);
                m = fmaf(f1.x, qv.x, 1.f); a2 = fmaf(rcpf_(m), qv.y, a2);
                m = fmaf(f1.y, qv.x, 1.f); a3 = fmaf(rcpf_(m), qv.y, a3);
                m = fmaf(f2.x, qv.x, 1.f); a4 = fmaf(rcpf_(m), qv.y, a4);
                m = fmaf(f2.y, qv.x, 1.f); a5 = fmaf(rcpf_(m), qv.y, a5);
                m = fmaf(f3.x, qv.x, 1.f); a6 = fmaf(rcpf_(m), qv.y, a6);
                m = fmaf(f3.y, qv.x, 1.f); a7 = fmaf(rcpf_(m), qv.y, a7);
            }
            float4* o = (float4*)(scratch + g*512 + q*8);
            o[0] = make_float4(a0,a1,a2,a3);
            o[1] = make_float4(a4,a5,a6,a7);
        }
        __syncthreads();
        // ---- B-reduce: score -> p = exp(score) (no max-shift; scores are O(±2)),
        //      wave-partial sums of p into red[0..7]
        if (tid < 512){
            float v = 0.f;
            #pragma unroll
            for (int g = 0; g < 16; g++) v += scratch[g*512 + tid];
            float p = ex2_(v * L2E);
            sc[tid] = p;
            float ss = p;
            #pragma unroll
            for (int off = 32; off; off >>= 1) ss += __shfl_xor(ss, off);
            if ((tid & 63) == 0) red[tid >> 6] = ss;
        }
        __syncthreads();

        // ---- phase C: ctx partials with raw p (normalization folded in later)
        {
            int eq = tid & 31;   // e-quad: e = 4*eq .. 4*eq+3
            int tg = tid >> 5;   // t-group: t in [16*tg, 16*tg+16)
            float4 acc = make_float4(0.f,0.f,0.f,0.f);
            const float4* ep = (const float4*)(enc + ((size_t)b*T_ + tg*16)*E_) + eq;
            #pragma unroll 4
            for (int i = 0; i < 16; i++){
                float w = sc[tg*16 + i];
                float4 ev = ep[(size_t)i * 32];
                acc.x = fmaf(w, ev.x, acc.x); acc.y = fmaf(w, ev.y, acc.y);
                acc.z = fmaf(w, ev.z, acc.z); acc.w = fmaf(w, ev.w, acc.w);
            }
            *(float4*)(scratch + tg*128 + eq*4) = acc;
        }
        __syncthreads();
        // ---- C-reduce: ctx[e] = (sum partials) / denom;  y-dot partials into red[16..17]
        if (tid < 128){
            float dn = red[0];
            #pragma unroll
            for (int i = 1; i < 8; i++) dn += red[i];
            float s = 0.f;
            #pragma unroll
            for (int tg = 0; tg < 32; tg++) s += scratch[tg*128 + tid];
            float ctxv = s * rcpf_(dn);
            ctx_s[tid] = ctxv;
            float yp = ctxv * Wc_s[1 + tid];
            #pragma unroll
            for (int off = 32; off; off >>= 1) yp += __shfl_xor(yp, off);
            if ((tid & 63) == 0) red[16 + (tid >> 6)] = yp;
        }
        __syncthreads();
        // ---- phase D: y, z = rz + y*Wk, gates (Keras i,f,g,o), update h,c
        if (tid < 128){
            float y = fmaf(lab_s[t], Wc_s[0], red[16] + red[17] + Wc_s[130]);
            float zi = rz[tid]       + y * Wk_s[tid];
            float zf = rz[128 + tid] + y * Wk_s[128 + tid];
            float zg = rz[256 + tid] + y * Wk_s[256 + tid];
            float zo = rz[384 + tid] + y * Wk_s[384 + tid];
            float si = rcpf_(1.f + ex2_(-L2E * zi));
            float sf = rcpf_(1.f + ex2_(-L2E * zf));
            float so = rcpf_(1.f + ex2_(-L2E * zo));
            float tg_ = 1.f - 2.f * rcpf_(ex2_(C2f * zg) + 1.f);
            float cn = sf * hc_s[128 + tid] + si * tg_;
            float tc = 1.f - 2.f * rcpf_(ex2_(C2f * cn) + 1.f);
            hc_s[128 + tid] = cn;
            hc_s[tid] = so * tc;
        }
        __syncthreads();
    }

    // ---- epilogue: pred = ([h, ctx] @ W1 + b1) @ W2 + b2
    if (tid < 128){
        float acc = b1[tid];
        for (int k = 0; k < 128; k++) acc = fmaf(hc_s[k],  W1[k*128 + tid], acc);
        for (int k = 0; k < 128; k++) acc = fmaf(ctx_s[k], W1[(128+k)*128 + tid], acc);
        scratch[tid] = acc * W2[tid];
    }
    __syncthreads();
    if (tid < 64){
        float a = scratch[tid] + scratch[64 + tid];
        #pragma unroll
        for (int off = 32; off; off >>= 1) a += __shfl_xor(a, off);
        if (tid == 0) out[b] = a + b2[0];
    }
}

extern "C" void kernel_launch(void* const* d_in, const int* in_sizes, int n_in,
                              void* d_out, int out_size, void* d_ws, size_t ws_size,
                              hipStream_t stream){
    const float* enc      = (const float*)d_in[0];
    const float* labels   = (const float*)d_in[1];
    const float* init_h   = (const float*)d_in[2];
    const float* init_c   = (const float*)d_in[3];
    const float* Wa = (const float*)d_in[5];
    const float* ba = (const float*)d_in[6];
    const float* Ua = (const float*)d_in[7];
    const float* bu = (const float*)d_in[8];
    const float* Va = (const float*)d_in[9];
    // d_in[10] = bv: softmax-shift-invariant, unused
    const float* Wc = (const float*)d_in[11];
    const float* bc = (const float*)d_in[12];
    const float* Wk = (const float*)d_in[13];
    const float* Wr = (const float*)d_in[14];
    const float* bl = (const float*)d_in[15];
    const float* W1 = (const float*)d_in[16];
    const float* b1 = (const float*)d_in[17];
    const float* W2 = (const float*)d_in[18];
    const float* b2 = (const float*)d_in[19];

    char* ws = (char*)d_ws;
    __half* P    = (__half*)ws;                          // 128*512*512*2 = 67108864 B
    __half* Wa_t = (__half*)(ws + 67108864);             // 512*256*2 = 262144 B
    __half* Wr_t = (__half*)(ws + 67108864 + 262144);    // 512*128*2 = 131072 B

    // Wa_t[n][k] = Wa[k][n] (K=256,N=512); Wr_t[m][k] = Wr[k][m] (K=128,N=512)
    transpose_half<<<dim3(16, 8, 1), 256, 0, stream>>>(Wa, Wa_t, 256, 512);
    transpose_half<<<dim3(16, 4, 1), 256, 0, stream>>>(Wr, Wr_t, 128, 512);

    dim3 g1(T_/64, T_/64, B_);
    uenc_kernel<<<g1, 256, 0, stream>>>(enc, Ua, bu, P);

    decoder_kernel<<<B_, 1024, 0, stream>>>(enc, labels, init_h, init_c,
        Va, ba, bl, Wc, bc, Wk, W1, b1, W2, b2,
        Wa_t, Wr_t, P, (float*)d_out);
}

// Round 3
// 13383.286 us; speedup vs baseline: 1.0634x; 1.0317x over previous
//
#include <hip/hip_runtime.h>
#include <hip/hip_fp16.h>

#define B_ 128
#define T_ 512
#define E_ 128
#define D_ 128

// exp2(C2*x) == e^(2x);  L2E = log2(e)
#define C2f 2.885390081777927f
#define L2E 1.4426950408889634f

__device__ __forceinline__ float rcpf_(float x){ return __builtin_amdgcn_rcpf(x); }
__device__ __forceinline__ float ex2_(float x){ return __builtin_amdgcn_exp2f(x); }

// device-scope (cross-XCD coherent) data/flag helpers
__device__ __forceinline__ void gstoref(float* p, float v){
    __hip_atomic_store(p, v, __ATOMIC_RELAXED, __HIP_MEMORY_SCOPE_AGENT);
}
__device__ __forceinline__ float gloadf(const float* p){
    return __hip_atomic_load(p, __ATOMIC_RELAXED, __HIP_MEMORY_SCOPE_AGENT);
}
__device__ __forceinline__ void flag_set(int* p, int v){
    __hip_atomic_store(p, v, __ATOMIC_RELEASE, __HIP_MEMORY_SCOPE_AGENT);
}
__device__ __forceinline__ void flag_wait(int* p, int v){
    int it = 0;
    while (__hip_atomic_load(p, __ATOMIC_ACQUIRE, __HIP_MEMORY_SCOPE_AGENT) < v
           && it < (1 << 26)){ it++; __builtin_amdgcn_s_sleep(2); }
}

// out[n][k] = (half) in[k][n],  K x N input, 32x32 tiles, 256 threads.
__global__ __launch_bounds__(256) void transpose_half(const float* __restrict__ in,
                                                      __half* __restrict__ out,
                                                      int K, int N){
    __shared__ float tile[32][33];
    int n0 = blockIdx.x * 32, k0 = blockIdx.y * 32;
    int tx = threadIdx.x & 31, ty = threadIdx.x >> 5;
    #pragma unroll
    for (int i = ty; i < 32; i += 8)
        tile[i][tx] = in[(size_t)(k0 + i) * N + n0 + tx];
    __syncthreads();
    #pragma unroll
    for (int i = ty; i < 32; i += 8)
        out[(size_t)(n0 + i) * K + k0 + tx] = __float2half(tile[tx][i]);
}

// fp16 copy of enc (for phase C streaming)
__global__ __launch_bounds__(256) void enc_to_half(const float* __restrict__ in,
                                                   __half* __restrict__ out){
    int i = (blockIdx.x * 256 + threadIdx.x) * 4;
    float4 v = *(const float4*)(in + i);
    __half2 a = __floats2half2_rn(v.x, v.y);
    __half2 b = __floats2half2_rn(v.z, v.w);
    *(__half2*)(out + i)     = a;
    *(__half2*)(out + i + 2) = b;
}

// P[b][n][t] = exp2(C2 * (sum_e enc[b][t][e]*Ua[e][n] + bu[n]))  as fp16
__global__ __launch_bounds__(256) void uenc_kernel(const float* __restrict__ enc,
                                                   const float* __restrict__ Ua,
                                                   const float* __restrict__ bu,
                                                   __half* __restrict__ P){
    int b = blockIdx.z;
    int t0 = blockIdx.x * 64;
    int n0 = blockIdx.y * 64;
    int tt = threadIdx.x & 63;
    int ng = threadIdx.x >> 6;
    const float* erow = enc + ((size_t)b * T_ + (t0 + tt)) * E_;
    const float* uap  = Ua + n0 + ng * 16;
    float acc[16];
    #pragma unroll
    for (int i = 0; i < 16; i++) acc[i] = 0.f;
    #pragma unroll 2
    for (int e0 = 0; e0 < E_; e0 += 4){
        float4 av = *(const float4*)(erow + e0);
        #pragma unroll
        for (int ee = 0; ee < 4; ee++){
            float a = (ee==0)?av.x:(ee==1)?av.y:(ee==2)?av.z:av.w;
            const float4* u4 = (const float4*)(uap + (size_t)(e0+ee) * T_);
            float4 x0 = u4[0], x1 = u4[1], x2 = u4[2], x3 = u4[3];
            acc[0]  = fmaf(a, x0.x, acc[0]);  acc[1]  = fmaf(a, x0.y, acc[1]);
            acc[2]  = fmaf(a, x0.z, acc[2]);  acc[3]  = fmaf(a, x0.w, acc[3]);
            acc[4]  = fmaf(a, x1.x, acc[4]);  acc[5]  = fmaf(a, x1.y, acc[5]);
            acc[6]  = fmaf(a, x1.z, acc[6]);  acc[7]  = fmaf(a, x1.w, acc[7]);
            acc[8]  = fmaf(a, x2.x, acc[8]);  acc[9]  = fmaf(a, x2.y, acc[9]);
            acc[10] = fmaf(a, x2.z, acc[10]); acc[11] = fmaf(a, x2.w, acc[11]);
            acc[12] = fmaf(a, x3.x, acc[12]); acc[13] = fmaf(a, x3.y, acc[13]);
            acc[14] = fmaf(a, x3.z, acc[14]); acc[15] = fmaf(a, x3.w, acc[15]);
        }
    }
    int nb = n0 + ng * 16;
    #pragma unroll
    for (int i = 0; i < 16; i++){
        float u = acc[i] + bu[nb + i];
        P[(size_t)b * T_ * T_ + (size_t)(nb + i) * T_ + t0 + tt] = __float2half(ex2_(C2f * u));
    }
}

__device__ __forceinline__ void dot8(float& acc, uint4 wv, float4 ha, float4 hb){
    float2 f0 = __half22float2(*reinterpret_cast<__half2*>(&wv.x));
    float2 f1 = __half22float2(*reinterpret_cast<__half2*>(&wv.y));
    float2 f2 = __half22float2(*reinterpret_cast<__half2*>(&wv.z));
    float2 f3 = __half22float2(*reinterpret_cast<__half2*>(&wv.w));
    acc = fmaf(ha.x, f0.x, acc); acc = fmaf(ha.y, f0.y, acc);
    acc = fmaf(ha.z, f1.x, acc); acc = fmaf(ha.w, f1.y, acc);
    acc = fmaf(hb.x, f2.x, acc); acc = fmaf(hb.y, f2.y, acc);
    acc = fmaf(hb.z, f3.x, acc); acc = fmaf(hb.w, f3.y, acc);
}

// grid (128, 2): b = blockIdx.x, half-id h = blockIdx.y. 1024 threads.
// LDS 146 KB -> hardware guarantees 1 block/CU -> all 256 blocks co-resident.
__global__ __launch_bounds__(1024) void decoder_kernel(
    const float* __restrict__ enc, const __half* __restrict__ enc_h, int use_f16,
    const float* __restrict__ labels,
    const float* __restrict__ init_h, const float* __restrict__ init_c,
    const float* __restrict__ Va,
    const float* __restrict__ ba, const float* __restrict__ bl,
    const float* __restrict__ Wc, const float* __restrict__ bc,
    const float* __restrict__ Wk,
    const float* __restrict__ W1, const float* __restrict__ b1,
    const float* __restrict__ W2, const float* __restrict__ b2,
    const __half* __restrict__ Wa_t, const __half* __restrict__ Wr_t,
    const __half* __restrict__ Pw,
    float* __restrict__ psbuf, float* __restrict__ ctxbuf,
    int* __restrict__ fA, int* __restrict__ fB,
    float* __restrict__ out)
{
    __shared__ __align__(16) __half Plds[96 * 512];   // 96 KB: LDS-resident P rows
    __shared__ __align__(16) float hc_s[256];         // h [0,128), c [128,256)
    __shared__ __align__(16) float ctx_s[128];
    __shared__ __align__(16) float2 QV[512];          // .x = Q[n] (own half), .y = -2*Va[n]
    __shared__ __align__(16) float sc[512];           // half-score -> p[t]
    __shared__ __align__(16) float rz[512];           // h@Wr + bl
    __shared__ __align__(16) float scratch[8192];     // 32 KB partials
    __shared__ __align__(16) float ba_s[512], bl_s[512], Wk_s[512], lab_s[512];
    __shared__ float Wc_s[132];
    __shared__ float red[20];

    const int tid = threadIdx.x;
    const int b = blockIdx.x;
    const int h_ = blockIdx.y;          // n-half / t-half id
    const int par_stride = B_ * 2;      // pair-slot layout

    if (tid < 128){
        hc_s[tid]       = init_h[b*128 + tid];
        hc_s[128 + tid] = init_c[b*128 + tid];
    }
    if (tid < 512){
        QV[tid].y = -2.f * Va[tid];
        ba_s[tid] = ba[tid];
        bl_s[tid] = bl[tid];
        Wk_s[tid] = Wk[tid];
        lab_s[tid] = labels[(size_t)b * T_ + tid];
    }
    if (tid < 129) Wc_s[tid] = Wc[tid];
    if (tid == 129) Wc_s[130] = bc[0];

    // block's n-half of P: rows n_loc in [0,256), global n = 256*h_ + n_loc
    const __half* Pb = Pw + ((size_t)b * T_ + 256 * h_) * T_;

    // Fill LDS-resident rows: n_loc = 16g + j for j<6  ->  lds row r = 6g + j
    {
        int wid = tid >> 6, lane = tid & 63;
        for (int r = wid; r < 96; r += 16){
            int g = r / 6, j = r - 6 * g;
            *((uint4*)Plds + (size_t)r * 64 + lane) =
                *((const uint4*)(Pb + (size_t)(16*g + j) * 512) + lane);
        }
    }
    __syncthreads();

    int* myfA = &fA[b*2 + h_];   int* pfA = &fA[b*2 + (1 - h_)];
    int* myfB = &fB[b*2 + h_];   int* pfB = &fB[b*2 + (1 - h_)];

    for (int t = 0; t < T_; t++){
        const int par = t & 1;
        float* psme = psbuf  + ((size_t)par * par_stride + b*2 + h_)      * 512;
        float* pspr = psbuf  + ((size_t)par * par_stride + b*2 + (1-h_))  * 512;
        float* cxme = ctxbuf + ((size_t)par * par_stride + b*2 + h_)      * 128;
        float* cxpr = ctxbuf + ((size_t)par * par_stride + b*2 + (1-h_))  * 128;

        // ---- phase A: s[n] for OWN n-half (k split 4-way) ; rz[m] full (dup)
        {
            const float4* hc4 = (const float4*)hc_s;
            {   // s: n' = tid&255 (own half), k-quarter kq = tid>>8
                int np = tid & 255, kq = tid >> 8;
                float acc = (kq == 0) ? ba_s[256*h_ + np] : 0.f;
                const uint4* wa = (const uint4*)(Wa_t + (size_t)(256*h_ + np) * 256 + kq * 64);
                #pragma unroll 4
                for (int i = 0; i < 8; i++){
                    uint4 wv = wa[i];
                    dot8(acc, wv, hc4[kq*16 + 2*i], hc4[kq*16 + 2*i + 1]);
                }
                scratch[kq*256 + np] = acc;
            }
            {   // rz: m = tid&511, k-half kh = tid>>9
                int m = tid & 511, kh = tid >> 9;
                float accr = (kh == 0) ? bl_s[m] : 0.f;
                const uint4* wr = (const uint4*)(Wr_t + (size_t)m * 128 + kh * 64);
                #pragma unroll 4
                for (int i = 0; i < 8; i++){
                    uint4 wv = wr[i];
                    dot8(accr, wv, hc4[kh*16 + 2*i], hc4[kh*16 + 2*i + 1]);
                }
                scratch[1024 + kh*512 + m] = accr;
            }
        }
        __syncthreads();
        if (tid < 256){
            float s = scratch[tid] + scratch[256+tid] + scratch[512+tid] + scratch[768+tid];
            QV[256*h_ + tid].x = ex2_(C2f * s);
        } else if (tid >= 512){
            int m = tid - 512;
            rz[m] = scratch[1024 + m] + scratch[1536 + m];
        }
        __syncthreads();

        // ---- phase B: half-score over own 256 n-rows; 6 LDS + 10 global rows/group
        {
            int q = tid & 63, g = tid >> 6;
            float a0=0.f,a1=0.f,a2=0.f,a3=0.f,a4=0.f,a5=0.f,a6=0.f,a7=0.f;
            const uint4* Pl = (const uint4*)Plds + (size_t)(6*g) * 64 + q;
            #pragma unroll
            for (int j = 0; j < 6; j++){
                uint4 pv = Pl[j * 64];
                float2 qv = QV[256*h_ + 16*g + j];
                float2 f0 = __half22float2(*reinterpret_cast<__half2*>(&pv.x));
                float2 f1 = __half22float2(*reinterpret_cast<__half2*>(&pv.y));
                float2 f2 = __half22float2(*reinterpret_cast<__half2*>(&pv.z));
                float2 f3 = __half22float2(*reinterpret_cast<__half2*>(&pv.w));
                float m;
                m = fmaf(f0.x, qv.x, 1.f); a0 = fmaf(rcpf_(m), qv.y, a0);
                m = fmaf(f0.y, qv.x, 1.f); a1 = fmaf(rcpf_(m), qv.y, a1);
                m = fmaf(f1.x, qv.x, 1.f); a2 = fmaf(rcpf_(m), qv.y, a2);
                m = fmaf(f1.y, qv.x, 1.f); a3 = fmaf(rcpf_(m), qv.y, a3);
                m = fmaf(f2.x, qv.x, 1.f); a4 = fmaf(rcpf_(m), qv.y, a4);
                m = fmaf(f2.y, qv.x, 1.f); a5 = fmaf(rcpf_(m), qv.y, a5);
                m = fmaf(f3.x, qv.x, 1.f); a6 = fmaf(rcpf_(m), qv.y, a6);
                m = fmaf(f3.y, qv.x, 1.f); a7 = fmaf(rcpf_(m), qv.y, a7);
            }
            const uint4* Pg = (const uint4*)Pb + (size_t)(16*g) * 64 + q;
            #pragma unroll 5
            for (int j = 6; j < 16; j++){
                uint4 pv = Pg[(size_t)j * 64];
                float2 qv = QV[256*h_ + 16*g + j];
                float2 f0 = __half22float2(*reinterpret_cast<__half2*>(&pv.x));
                float2 f1 = __half22float2(*reinterpret_cast<__half2*>(&pv.y));
                float2 f2 = __half22float2(*reinterpret_cast<__half2*>(&pv.z));
                float2 f3 = __half22float2(*reinterpret_cast<__half2*>(&pv.w));
                float m;
                m = fmaf(f0.x, qv.x, 1.f); a0 = fmaf(rcpf_(m), qv.y, a0);
                m = fmaf(f0.y, qv.x, 1.f); a1 = fmaf(rcpf_(m), qv.y, a1);
                m = fmaf(f1.x, qv.x, 1.f); a2 = fmaf(rcpf_(m), qv.y, a2);
                m = fmaf(f1.y, qv.x, 1.f); a3 = fmaf(rcpf_(m), qv.y, a3);
                m = fmaf(f2.x, qv.x, 1.f); a4 = fmaf(rcpf_(m), qv.y, a4);
                m = fmaf(f2.y, qv.x, 1.f); a5 = fmaf(rcpf_(m), qv.y, a5);
                m = fmaf(f3.x, qv.x, 1.f); a6 = fmaf(rcpf_(m), qv.y, a6);
                m = fmaf(f3.y, qv.x, 1.f); a7 = fmaf(rcpf_(m), qv.y, a7);
            }
            float4* o = (float4*)(scratch + g*512 + q*8);
            o[0] = make_float4(a0,a1,a2,a3);
            o[1] = make_float4(a4,a5,a6,a7);
        }
        __syncthreads();
        // ---- B-reduce -> half-score; publish to partner
        if (tid < 512){
            float v = 0.f;
            #pragma unroll
            for (int g = 0; g < 16; g++) v += scratch[g*512 + tid];
            sc[tid] = v;
            gstoref(&psme[tid], v);
        }
        __syncthreads();
        if (tid == 0){ flag_set(myfA, t + 1); flag_wait(pfA, t + 1); }
        __syncthreads();
        // ---- full score -> p; denominator partials
        if (tid < 512){
            float score = sc[tid] + gloadf(&pspr[tid]);
            float p = ex2_(score * L2E);
            sc[tid] = p;
            float ss = p;
            #pragma unroll
            for (int off = 32; off; off >>= 1) ss += __shfl_xor(ss, off);
            if ((tid & 63) == 0) red[tid >> 6] = ss;
        }
        __syncthreads();

        // ---- phase C: ctx partials over OWN t-half (256 t's)
        {
            int eq = tid & 31, tg = tid >> 5;      // 32 groups x 8 rows
            int t0r = 256*h_ + tg*8;
            float4 acc = make_float4(0.f,0.f,0.f,0.f);
            if (use_f16){
                const uint2* ep = (const uint2*)(enc_h + ((size_t)b*T_ + t0r)*E_) + eq;
                #pragma unroll
                for (int i = 0; i < 8; i++){
                    float w = sc[t0r + i];
                    uint2 ev = ep[(size_t)i * 32];
                    float2 e01 = __half22float2(*reinterpret_cast<__half2*>(&ev.x));
                    float2 e23 = __half22float2(*reinterpret_cast<__half2*>(&ev.y));
                    acc.x = fmaf(w, e01.x, acc.x); acc.y = fmaf(w, e01.y, acc.y);
                    acc.z = fmaf(w, e23.x, acc.z); acc.w = fmaf(w, e23.y, acc.w);
                }
            } else {
                const float4* ep = (const float4*)(enc + ((size_t)b*T_ + t0r)*E_) + eq;
                #pragma unroll
                for (int i = 0; i < 8; i++){
                    float w = sc[t0r + i];
                    float4 ev = ep[(size_t)i * 32];
                    acc.x = fmaf(w, ev.x, acc.x); acc.y = fmaf(w, ev.y, acc.y);
                    acc.z = fmaf(w, ev.z, acc.z); acc.w = fmaf(w, ev.w, acc.w);
                }
            }
            *(float4*)(scratch + tg*128 + eq*4) = acc;
        }
        __syncthreads();
        // ---- C-reduce: ctx half-partial; publish
        if (tid < 128){
            float s = 0.f;
            #pragma unroll
            for (int tg = 0; tg < 32; tg++) s += scratch[tg*128 + tid];
            ctx_s[tid] = s;
            gstoref(&cxme[tid], s);
        }
        __syncthreads();
        if (tid == 0){ flag_set(myfB, t + 1); flag_wait(pfB, t + 1); }
        __syncthreads();
        // ---- combine ctx, y-dot
        if (tid < 128){
            float dn = red[0];
            #pragma unroll
            for (int i = 1; i < 8; i++) dn += red[i];
            float ctxv = (ctx_s[tid] + gloadf(&cxpr[tid])) * rcpf_(dn);
            ctx_s[tid] = ctxv;
            float yp = ctxv * Wc_s[1 + tid];
            #pragma unroll
            for (int off = 32; off; off >>= 1) yp += __shfl_xor(yp, off);
            if ((tid & 63) == 0) red[16 + (tid >> 6)] = yp;
        }
        __syncthreads();
        // ---- phase D: gates (Keras i,f,g,o), update h,c   (dup in both blocks)
        if (tid < 128){
            float y = fmaf(lab_s[t], Wc_s[0], red[16] + red[17] + Wc_s[130]);
            float zi = rz[tid]       + y * Wk_s[tid];
            float zf = rz[128 + tid] + y * Wk_s[128 + tid];
            float zg = rz[256 + tid] + y * Wk_s[256 + tid];
            float zo = rz[384 + tid] + y * Wk_s[384 + tid];
            float si = rcpf_(1.f + ex2_(-L2E * zi));
            float sf = rcpf_(1.f + ex2_(-L2E * zf));
            float so = rcpf_(1.f + ex2_(-L2E * zo));
            float tg_ = 1.f - 2.f * rcpf_(ex2_(C2f * zg) + 1.f);
            float cn = sf * hc_s[128 + tid] + si * tg_;
            float tc = 1.f - 2.f * rcpf_(ex2_(C2f * cn) + 1.f);
            hc_s[128 + tid] = cn;
            hc_s[tid] = so * tc;
        }
        __syncthreads();
    }

    // ---- epilogue: pred = ([h, ctx] @ W1 + b1) @ W2 + b2   (h_==0 writes)
    if (tid < 128){
        float acc = b1[tid];
        for (int k = 0; k < 128; k++) acc = fmaf(hc_s[k],  W1[k*128 + tid], acc);
        for (int k = 0; k < 128; k++) acc = fmaf(ctx_s[k], W1[(128+k)*128 + tid], acc);
        scratch[tid] = acc * W2[tid];
    }
    __syncthreads();
    if (h_ == 0 && tid < 64){
        float a = scratch[tid] + scratch[64 + tid];
        #pragma unroll
        for (int off = 32; off; off >>= 1) a += __shfl_xor(a, off);
        if (tid == 0) out[b] = a + b2[0];
    }
}

extern "C" void kernel_launch(void* const* d_in, const int* in_sizes, int n_in,
                              void* d_out, int out_size, void* d_ws, size_t ws_size,
                              hipStream_t stream){
    const float* enc      = (const float*)d_in[0];
    const float* labels   = (const float*)d_in[1];
    const float* init_h   = (const float*)d_in[2];
    const float* init_c   = (const float*)d_in[3];
    const float* Wa = (const float*)d_in[5];
    const float* ba = (const float*)d_in[6];
    const float* Ua = (const float*)d_in[7];
    const float* bu = (const float*)d_in[8];
    const float* Va = (const float*)d_in[9];
    // d_in[10] = bv: softmax-shift-invariant, unused
    const float* Wc = (const float*)d_in[11];
    const float* bc = (const float*)d_in[12];
    const float* Wk = (const float*)d_in[13];
    const float* Wr = (const float*)d_in[14];
    const float* bl = (const float*)d_in[15];
    const float* W1 = (const float*)d_in[16];
    const float* b1 = (const float*)d_in[17];
    const float* W2 = (const float*)d_in[18];
    const float* b2 = (const float*)d_in[19];

    char* ws = (char*)d_ws;
    const size_t szP = (size_t)B_ * T_ * T_ * 2;       // 67,108,864
    const size_t szWa = 512 * 256 * 2;                 // 262,144
    const size_t szWr = 512 * 128 * 2;                 // 131,072
    const size_t base = szP + szWa + szWr;             // 67,502,080
    const size_t szEnc = (size_t)B_ * T_ * E_ * 2;     // 16,777,216
    const size_t commSz = 2*256*512*4 + 2*256*128*4 + 512*4; // 1,050,624 + 262,144 + 2,048

    __half* P    = (__half*)ws;
    __half* Wa_t = (__half*)(ws + szP);
    __half* Wr_t = (__half*)(ws + szP + szWa);

    int use_f16 = (ws_size >= base + szEnc + commSz) ? 1 : 0;
    __half* enc_h = (__half*)(ws + base);
    size_t comm0 = use_f16 ? (base + szEnc) : base;
    float* psbuf  = (float*)(ws + comm0);
    float* ctxbuf = psbuf + 2*256*512;
    int*   flags  = (int*)(ctxbuf + 2*256*128);
    int* fA = flags;           // [128][2]
    int* fB = flags + 256;     // [128][2]

    hipMemsetAsync(flags, 0, 512 * sizeof(int), stream);

    transpose_half<<<dim3(16, 8, 1), 256, 0, stream>>>(Wa, Wa_t, 256, 512);
    transpose_half<<<dim3(16, 4, 1), 256, 0, stream>>>(Wr, Wr_t, 128, 512);
    if (use_f16)
        enc_to_half<<<8192, 256, 0, stream>>>(enc, enc_h);

    dim3 g1(T_/64, T_/64, B_);
    uenc_kernel<<<g1, 256, 0, stream>>>(enc, Ua, bu, P);

    decoder_kernel<<<dim3(B_, 2), 1024, 0, stream>>>(enc, enc_h, use_f16,
        labels, init_h, init_c, Va, ba, bl, Wc, bc, Wk, W1, b1, W2, b2,
        Wa_t, Wr_t, P, psbuf, ctxbuf, fA, fB, (float*)d_out);
}